// Round 1
// baseline (32.583 us; speedup 1.0000x reference)
//
#include <hip/hip_runtime.h>

// SPD 2x2 matrix-log (closed form) + Linear(3,17), fused, memory-bound.
//
// For symmetric 2x2 X = [[a,b],[b,c]]:
//   m = (a+c)/2, h = (a-c)/2, disc = sqrt(h^2 + b^2)
//   lam1 = m + disc, lam2 = det/lam1  (robust; SPD => lam2 > 0)
//   log(X) = p*I + r*(X - m*I),  p = (log l1 + log l2)/2, r = (log l1 - log l2)/(2*disc)
// vec = [L00, sqrt2*L01, L11];  out = vec @ W^T + bias.

#define SQRT2F 1.41421356237309504880f

__global__ __launch_bounds__(256) void spd_log_linear_kernel(
    const float4* __restrict__ x,      // [B] of (x00,x01,x10,x11)
    const float*  __restrict__ W,      // [17*3]
    const float*  __restrict__ bias,   // [17]
    float*        __restrict__ out)    // [B*17]
{
    __shared__ float sW[17 * 3];
    __shared__ float sb[17];
    __shared__ float sout[256 * 17];   // 17408 B

    const int t = threadIdx.x;
    if (t < 51) sW[t] = W[t];
    if (t < 17) sb[t] = bias[t];

    const long long gid = (long long)blockIdx.x * 256 + t;
    const float4 xv = x[gid];
    const float a = xv.x, b = xv.y, c = xv.w;   // symmetric: xv.z == xv.y

    const float m    = 0.5f * (a + c);
    const float h    = 0.5f * (a - c);
    const float disc = sqrtf(fmaf(h, h, b * b));
    const float lam1 = m + disc;
    const float det  = fmaf(a, c, -b * b);
    const float lam2 = det / lam1;               // robust small eigenvalue
    const float l1 = logf(lam1);
    const float l2 = logf(lam2);
    const float p  = 0.5f * (l1 + l2);
    const float q  = 0.5f * (l1 - l2);
    const float r  = (disc > 1e-20f) ? (q / disc) : (1.0f / m);

    const float v0 = p + r * h;          // L00
    const float v1 = SQRT2F * r * b;     // sqrt2 * L01
    const float v2 = p - r * h;          // L11

    __syncthreads();   // sW/sb ready

    // Per-row 17 outputs into LDS. stride 17 (odd) -> conflict-free within
    // 32-lane groups; lanes t and t+32 alias the same bank (2-way = free).
    #pragma unroll
    for (int j = 0; j < 17; ++j) {
        sout[t * 17 + j] = fmaf(v0, sW[j * 3 + 0],
                           fmaf(v1, sW[j * 3 + 1],
                           fmaf(v2, sW[j * 3 + 2], sb[j])));
    }
    __syncthreads();

    // Coalesced drain: 256*17 = 4352 floats = 1088 float4 per block.
    float4* outv = (float4*)(out + (long long)blockIdx.x * 4352);
    const float4* sv = (const float4*)sout;
    #pragma unroll
    for (int k = 0; k < 4; ++k) outv[t + k * 256] = sv[t + k * 256];
    if (t < 64) outv[1024 + t] = sv[1024 + t];
}

extern "C" void kernel_launch(void* const* d_in, const int* in_sizes, int n_in,
                              void* d_out, int out_size, void* d_ws, size_t ws_size,
                              hipStream_t stream) {
    const float* x = (const float*)d_in[0];   // [B,2,2]
    const float* W = (const float*)d_in[1];   // [17,3]
    const float* b = (const float*)d_in[2];   // [17]
    float* out = (float*)d_out;               // [B,17]

    const int B = in_sizes[0] / 4;            // 2097152
    const int blocks = B / 256;               // B divisible by 256 (2097152 = 8192*256)

    spd_log_linear_kernel<<<blocks, 256, 0, stream>>>(
        (const float4*)x, W, b, out);
}